// Round 4
// baseline (8060.557 us; speedup 1.0000x reference)
//
#include <hip/hip_runtime.h>
#include <stdint.h>

#define B_ 128
#define T_ 512
#define D_ 1024
#define H_ 1024

typedef __attribute__((ext_vector_type(8))) short bf16x8;
typedef __attribute__((ext_vector_type(4))) float f32x4;
typedef unsigned int u32;
typedef unsigned long long u64;

__device__ __forceinline__ ushort f2bf(float f) {
  union { float f; uint32_t u; } v; v.f = f;
  uint32_t u = v.u + 0x7FFFu + ((v.u >> 16) & 1u);
  return (ushort)(u >> 16);
}
__device__ __forceinline__ float bf2f(ushort s) {
  union { uint32_t u; float f; } v; v.u = ((uint32_t)s) << 16;
  return v.f;
}

__device__ __forceinline__ void store_xp(float* p, float v) { *p = v; }
__device__ __forceinline__ void store_xp(ushort* p, float v) { *p = f2bf(v); }
__device__ __forceinline__ float load_xp(const float* p) { return *p; }
__device__ __forceinline__ float load_xp(const ushort* p) { return bf2f(*p); }

// ---------------- W_hh -> (hi, lo) bf16 split ----------------
__global__ void wsplit_kernel(const float* __restrict__ W,
                              ushort* __restrict__ hi, ushort* __restrict__ lo,
                              int n) {
  int i = blockIdx.x * blockDim.x + threadIdx.x;
  if (i < n) {
    float w = W[i];
    ushort h = f2bf(w);
    hi[i] = h;
    lo[i] = f2bf(w - bf2f(h));
  }
}

// ---------------- zero workspace region ----------------
__global__ void hzero_kernel(uint4* __restrict__ p, int n4) {
  int i = blockIdx.x * blockDim.x + threadIdx.x;
  if (i < n4) p[i] = make_uint4(0, 0, 0, 0);
}

// ---------------- xp = x @ W_ih^T + b_ih + b_hh, stored [T,B,H] ----------------
template <typename XPT>
__global__ __launch_bounds__(256) void xp_gemm(
    const float* __restrict__ x, const float* __restrict__ Wih,
    const float* __restrict__ bih, const float* __restrict__ bhh,
    XPT* __restrict__ xp) {
  __shared__ __align__(16) ushort As[128][40];
  __shared__ __align__(16) ushort Bs[128][40];
  const int tid = threadIdx.x;
  const int lane = tid & 63;
  const int w = tid >> 6;
  const int wm = w >> 1, wn = w & 1;
  const int bm = blockIdx.x;  // 512 M-tiles
  const int bn = blockIdx.y;  // 8 N-tiles

  f32x4 acc[4][4] = {};

  for (int kt = 0; kt < D_ / 32; ++kt) {
    __syncthreads();
#pragma unroll
    for (int i = 0; i < 4; ++i) {
      int c = tid + i * 256;      // 0..1023
      int isB = c >> 9;           // 0: A chunk, 1: B chunk
      int cc = c & 511;
      int row = cc >> 2;          // 0..127
      int col8 = (cc & 3) << 3;   // 0,8,16,24
      const float* src = isB
          ? (Wih + (size_t)(bn * 128 + row) * D_ + kt * 32 + col8)
          : (x + (size_t)(bm * 128 + row) * D_ + kt * 32 + col8);
      float4 f0 = *(const float4*)(src);
      float4 f1 = *(const float4*)(src + 4);
      uint32_t p0 = (uint32_t)f2bf(f0.x) | ((uint32_t)f2bf(f0.y) << 16);
      uint32_t p1 = (uint32_t)f2bf(f0.z) | ((uint32_t)f2bf(f0.w) << 16);
      uint32_t p2 = (uint32_t)f2bf(f1.x) | ((uint32_t)f2bf(f1.y) << 16);
      uint32_t p3 = (uint32_t)f2bf(f1.z) | ((uint32_t)f2bf(f1.w) << 16);
      uint4 pk = make_uint4(p0, p1, p2, p3);
      ushort* dst = isB ? &Bs[row][col8] : &As[row][col8];
      *(uint4*)dst = pk;
    }
    __syncthreads();

    bf16x8 af[4], bfr[4];
#pragma unroll
    for (int fm = 0; fm < 4; ++fm)
      af[fm] = *(const bf16x8*)&As[wm * 64 + fm * 16 + (lane & 15)][(lane >> 4) * 8];
#pragma unroll
    for (int fn = 0; fn < 4; ++fn)
      bfr[fn] = *(const bf16x8*)&Bs[wn * 64 + fn * 16 + (lane & 15)][(lane >> 4) * 8];
#pragma unroll
    for (int fm = 0; fm < 4; ++fm)
#pragma unroll
      for (int fn = 0; fn < 4; ++fn)
        acc[fm][fn] = __builtin_amdgcn_mfma_f32_16x16x32_bf16(
            af[fm], bfr[fn], acc[fm][fn], 0, 0, 0);
  }

  float bias[4];
#pragma unroll
  for (int fn = 0; fn < 4; ++fn) {
    int j = bn * 128 + wn * 64 + fn * 16 + (lane & 15);
    bias[fn] = bih[j] + bhh[j];
  }
#pragma unroll
  for (int fm = 0; fm < 4; ++fm) {
#pragma unroll
    for (int r = 0; r < 4; ++r) {
      int m = bm * 128 + wm * 64 + fm * 16 + ((lane >> 4) * 4) + r;
      int t = m & (T_ - 1);
      int b = m >> 9;  // m / T_
      size_t base = (size_t)t * (B_ * H_) + (size_t)b * H_;
#pragma unroll
      for (int fn = 0; fn < 4; ++fn) {
        int j = bn * 128 + wn * 64 + fn * 16 + (lane & 15);
        store_xp(xp + base + j, acc[fm][fn][r] + bias[fn]);
      }
    }
  }
}

// ---------------- persistent recurrence v3: tagged-data poll ----------------
// 256 WGs: replica = bid&7 (16 batches), col-group wgc = bid>>3 (32 cols).
// Wave = K-quarter. W_hh frags in registers. h exchanged as tagged u64
// {lo32 = packed bf16 hi|lo, hi32 = step tag} via relaxed AGENT atomics.
// The poll load IS the data load (each u64 self-validating) -> no flags,
// no writer-side vmcnt, no flag->data chain. Epilogue parallel on 4 waves;
// K-reduce LDS double-buffered by step parity (one barrier/step).
template <typename XPT>
__global__ __launch_bounds__(256, 1) void rnn_persist(
    const ushort* __restrict__ Whi, const ushort* __restrict__ Wlo,
    const XPT* __restrict__ xp,
    u64* __restrict__ Htag,   // [2][B_][H_]
    float* __restrict__ out) {
  __shared__ __align__(16) f32x4 red[2][4][2][64];  // 16 KB

  const int bid = blockIdx.x;
  const int rep = bid & 7;    // batches [rep*16, rep*16+16)
  const int wgc = bid >> 3;   // cols [wgc*32, wgc*32+32)
  const int tid = threadIdx.x;
  const int lane = tid & 63;
  const int kq = tid >> 6;    // wave = K-quarter
  const int r16 = lane & 15;
  const int kg = lane >> 4;   // 0..3
  const int nf_e = kq & 1;    // epilogue: this wave's nf slice
  const int rh_e = kq >> 1;   // epilogue: this wave's row pair

  // ---- preload W fragments into registers (128 VGPR) ----
  bf16x8 wbh[8][2], wbl[8][2];
#pragma unroll
  for (int ks = 0; ks < 8; ++ks) {
#pragma unroll
    for (int nf = 0; nf < 2; ++nf) {
      int col = wgc * 32 + nf * 16 + r16;
      int k = kq * 256 + ks * 32 + kg * 8;
      wbh[ks][nf] = *(const bf16x8*)(Whi + (size_t)col * H_ + k);
      wbl[ks][nf] = *(const bf16x8*)(Wlo + (size_t)col * H_ + k);
    }
  }

  const int arow = rep * 16 + r16;
  const size_t hbase = (size_t)arow * H_ + kq * 256 + kg * 8;  // u64 index
  const int erow0 = rep * 16 + kg * 4 + rh_e * 2;
  const int ecol = wgc * 32 + nf_e * 16 + r16;

  for (int t = 0; t < T_; ++t) {
    const u64* Hq = Htag + (size_t)(t & 1) * (B_ * H_);
    u64* Hn = Htag + (size_t)((t + 1) & 1) * (B_ * H_);

    // xp prefetch (independent of h; off critical path)
    float xpv[2];
#pragma unroll
    for (int e = 0; e < 2; ++e)
      xpv[e] = load_xp(xp + (size_t)t * (B_ * H_) + (size_t)(erow0 + e) * H_ + ecol);

    // ---- poll + load h quarter: 64 tagged u64 per lane ----
    u64 aq[8][8];
    const u32 tg = (u32)t;
    for (;;) {
#pragma unroll
      for (int ks = 0; ks < 8; ++ks)
#pragma unroll
        for (int j = 0; j < 8; ++j)
          aq[ks][j] = __hip_atomic_load(Hq + hbase + ks * 32 + j,
                                        __ATOMIC_RELAXED, __HIP_MEMORY_SCOPE_AGENT);
      u32 bad = 0;
#pragma unroll
      for (int ks = 0; ks < 8; ++ks)
#pragma unroll
        for (int j = 0; j < 8; ++j)
          bad |= ((u32)(aq[ks][j] >> 32)) ^ tg;
      if (__all(bad == 0)) break;
      __builtin_amdgcn_s_sleep(2);
    }

    // ---- unpack + MFMA ----
    f32x4 acc[2] = {};
#pragma unroll
    for (int ks = 0; ks < 8; ++ks) {
      union { u32 u[4]; bf16x8 v; } ah, al;
#pragma unroll
      for (int m = 0; m < 4; ++m) {
        u32 e0 = (u32)aq[ks][2 * m];
        u32 e1 = (u32)aq[ks][2 * m + 1];
        ah.u[m] = __builtin_amdgcn_perm(e1, e0, 0x05040100u);  // hi bf16 pair
        al.u[m] = __builtin_amdgcn_perm(e1, e0, 0x07060302u);  // lo bf16 pair
      }
#pragma unroll
      for (int nf = 0; nf < 2; ++nf) {
        acc[nf] = __builtin_amdgcn_mfma_f32_16x16x32_bf16(ah.v, wbh[ks][nf], acc[nf], 0, 0, 0);
        acc[nf] = __builtin_amdgcn_mfma_f32_16x16x32_bf16(al.v, wbh[ks][nf], acc[nf], 0, 0, 0);
        acc[nf] = __builtin_amdgcn_mfma_f32_16x16x32_bf16(ah.v, wbl[ks][nf], acc[nf], 0, 0, 0);
      }
    }

    // ---- all-to-all K reduce (parity double-buffered) ----
    const int par = t & 1;
    red[par][kq][0][lane] = acc[0];
    red[par][kq][1][lane] = acc[1];
    __syncthreads();

    // ---- parallel epilogue: each wave 2 outputs/lane ----
#pragma unroll
    for (int e = 0; e < 2; ++e) {
      int r = rh_e * 2 + e;
      float s = red[par][0][nf_e][lane][r] + red[par][1][nf_e][lane][r]
              + red[par][2][nf_e][lane][r] + red[par][3][nf_e][lane][r];
      float pre = s + xpv[e];
      float hn = tanhf(pre);
      ushort hb = f2bf(hn);
      ushort lb = f2bf(hn - bf2f(hb));
      u32 pk = (u32)hb | ((u32)lb << 16);
      u64 val = (u64)pk | ((u64)(u32)(t + 1) << 32);
      __hip_atomic_store(Hn + (size_t)(erow0 + e) * H_ + ecol, val,
                         __ATOMIC_RELAXED, __HIP_MEMORY_SCOPE_AGENT);
      if (t == T_ - 1) out[(size_t)(erow0 + e) * H_ + ecol] = hn;
    }
    // no second barrier, no vmcnt: readers self-gate on tags;
    // store latency overlaps next step's poll.
  }
}

// ---------------- launch ----------------
extern "C" void kernel_launch(void* const* d_in, const int* in_sizes, int n_in,
                              void* d_out, int out_size, void* d_ws, size_t ws_size,
                              hipStream_t stream) {
  const float* x    = (const float*)d_in[0];
  const float* W_ih = (const float*)d_in[1];
  const float* W_hh = (const float*)d_in[2];
  const float* b_ih = (const float*)d_in[3];
  const float* b_hh = (const float*)d_in[4];
  float* out = (float*)d_out;

  const size_t xp_f32_bytes = (size_t)T_ * B_ * H_ * 4;   // 256 MB
  const size_t xp_bf_bytes  = xp_f32_bytes / 2;           // 128 MB
  const size_t wsp_bytes    = 2 * (size_t)H_ * H_ * 2;    // 4 MB (hi+lo)
  const size_t htag_bytes   = 2 * (size_t)B_ * H_ * 8;    // 2 MB tagged, dbuf

  bool fp32xp = ws_size >= xp_f32_bytes + wsp_bytes + htag_bytes;
  bool bf16xp = !fp32xp && ws_size >= xp_bf_bytes + wsp_bytes + htag_bytes;
  if (!fp32xp && !bf16xp) return;

  char* p = (char*)d_ws;
  size_t xp_bytes = fp32xp ? xp_f32_bytes : xp_bf_bytes;
  char* xp_raw = p;                       p += xp_bytes;
  ushort* Whi = (ushort*)p;               p += (size_t)H_ * H_ * 2;
  ushort* Wlo = (ushort*)p;               p += (size_t)H_ * H_ * 2;
  u64* Htag = (u64*)p;

  // 1) split W_hh
  {
    int n = H_ * H_;
    wsplit_kernel<<<(n + 255) / 256, 256, 0, stream>>>(W_hh, Whi, Wlo, n);
  }
  // 2) zero Htag (tags=0 == "step 0 ready", h=0)
  {
    int n4 = (int)(htag_bytes / 16);
    hzero_kernel<<<(n4 + 255) / 256, 256, 0, stream>>>((uint4*)Htag, n4);
  }
  // 3) xp GEMM
  dim3 gxp(512, 8);
  if (fp32xp)
    xp_gemm<float><<<gxp, 256, 0, stream>>>(x, W_ih, b_ih, b_hh, (float*)xp_raw);
  else
    xp_gemm<ushort><<<gxp, 256, 0, stream>>>(x, W_ih, b_ih, b_hh, (ushort*)xp_raw);

  // 4) persistent recurrence (256 WGs, 1 WG/CU)
  if (fp32xp)
    rnn_persist<float><<<256, 256, 0, stream>>>(Whi, Wlo, (const float*)xp_raw, Htag, out);
  else
    rnn_persist<ushort><<<256, 256, 0, stream>>>(Whi, Wlo, (const ushort*)xp_raw, Htag, out);
}

// Round 7
// 2765.719 us; speedup vs baseline: 2.9145x; 2.9145x over previous
//
#include <hip/hip_runtime.h>
#include <stdint.h>

#define B_ 128
#define T_ 512
#define D_ 1024
#define H_ 1024

typedef __attribute__((ext_vector_type(8))) short bf16x8;
typedef __attribute__((ext_vector_type(4))) float f32x4;
typedef unsigned int u32;
typedef unsigned long long u64;
typedef __attribute__((ext_vector_type(4))) u32 u32x4;

__device__ __forceinline__ ushort f2bf(float f) {
  union { float f; uint32_t u; } v; v.f = f;
  uint32_t u = v.u + 0x7FFFu + ((v.u >> 16) & 1u);
  return (ushort)(u >> 16);
}
__device__ __forceinline__ float bf2f(ushort s) {
  union { uint32_t u; float f; } v; v.u = ((uint32_t)s) << 16;
  return v.f;
}

__device__ __forceinline__ void store_xp(float* p, float v) { *p = v; }
__device__ __forceinline__ void store_xp(ushort* p, float v) { *p = f2bf(v); }
__device__ __forceinline__ float load_xp(const float* p) { return *p; }
__device__ __forceinline__ float load_xp(const ushort* p) { return bf2f(*p); }

// ---------------- W_hh -> (hi, lo) bf16 split ----------------
__global__ void wsplit_kernel(const float* __restrict__ W,
                              ushort* __restrict__ hi, ushort* __restrict__ lo,
                              int n) {
  int i = blockIdx.x * blockDim.x + threadIdx.x;
  if (i < n) {
    float w = W[i];
    ushort h = f2bf(w);
    hi[i] = h;
    lo[i] = f2bf(w - bf2f(h));
  }
}

// ---------------- zero workspace region ----------------
__global__ void hzero_kernel(uint4* __restrict__ p, int n4) {
  int i = blockIdx.x * blockDim.x + threadIdx.x;
  if (i < n4) p[i] = make_uint4(0, 0, 0, 0);
}

// ---------------- xp = x @ W_ih^T + b_ih + b_hh, stored [T,B,H] ----------------
template <typename XPT>
__global__ __launch_bounds__(256) void xp_gemm(
    const float* __restrict__ x, const float* __restrict__ Wih,
    const float* __restrict__ bih, const float* __restrict__ bhh,
    XPT* __restrict__ xp) {
  __shared__ __align__(16) ushort As[128][40];
  __shared__ __align__(16) ushort Bs[128][40];
  const int tid = threadIdx.x;
  const int lane = tid & 63;
  const int w = tid >> 6;
  const int wm = w >> 1, wn = w & 1;
  const int bm = blockIdx.x;  // 512 M-tiles
  const int bn = blockIdx.y;  // 8 N-tiles

  f32x4 acc[4][4] = {};

  for (int kt = 0; kt < D_ / 32; ++kt) {
    __syncthreads();
#pragma unroll
    for (int i = 0; i < 4; ++i) {
      int c = tid + i * 256;      // 0..1023
      int isB = c >> 9;           // 0: A chunk, 1: B chunk
      int cc = c & 511;
      int row = cc >> 2;          // 0..127
      int col8 = (cc & 3) << 3;   // 0,8,16,24
      const float* src = isB
          ? (Wih + (size_t)(bn * 128 + row) * D_ + kt * 32 + col8)
          : (x + (size_t)(bm * 128 + row) * D_ + kt * 32 + col8);
      float4 f0 = *(const float4*)(src);
      float4 f1 = *(const float4*)(src + 4);
      uint32_t p0 = (uint32_t)f2bf(f0.x) | ((uint32_t)f2bf(f0.y) << 16);
      uint32_t p1 = (uint32_t)f2bf(f0.z) | ((uint32_t)f2bf(f0.w) << 16);
      uint32_t p2 = (uint32_t)f2bf(f1.x) | ((uint32_t)f2bf(f1.y) << 16);
      uint32_t p3 = (uint32_t)f2bf(f1.z) | ((uint32_t)f2bf(f1.w) << 16);
      uint4 pk = make_uint4(p0, p1, p2, p3);
      ushort* dst = isB ? &Bs[row][col8] : &As[row][col8];
      *(uint4*)dst = pk;
    }
    __syncthreads();

    bf16x8 af[4], bfr[4];
#pragma unroll
    for (int fm = 0; fm < 4; ++fm)
      af[fm] = *(const bf16x8*)&As[wm * 64 + fm * 16 + (lane & 15)][(lane >> 4) * 8];
#pragma unroll
    for (int fn = 0; fn < 4; ++fn)
      bfr[fn] = *(const bf16x8*)&Bs[wn * 64 + fn * 16 + (lane & 15)][(lane >> 4) * 8];
#pragma unroll
    for (int fm = 0; fm < 4; ++fm)
#pragma unroll
      for (int fn = 0; fn < 4; ++fn)
        acc[fm][fn] = __builtin_amdgcn_mfma_f32_16x16x32_bf16(
            af[fm], bfr[fn], acc[fm][fn], 0, 0, 0);
  }

  float bias[4];
#pragma unroll
  for (int fn = 0; fn < 4; ++fn) {
    int j = bn * 128 + wn * 64 + fn * 16 + (lane & 15);
    bias[fn] = bih[j] + bhh[j];
  }
#pragma unroll
  for (int fm = 0; fm < 4; ++fm) {
#pragma unroll
    for (int r = 0; r < 4; ++r) {
      int m = bm * 128 + wm * 64 + fm * 16 + ((lane >> 4) * 4) + r;
      int t = m & (T_ - 1);
      int b = m >> 9;  // m / T_
      size_t base = (size_t)t * (B_ * H_) + (size_t)b * H_;
#pragma unroll
      for (int fn = 0; fn < 4; ++fn) {
        int j = bn * 128 + wn * 64 + fn * 16 + (lane & 15);
        store_xp(xp + base + j, acc[fm][fn][r] + bias[fn]);
      }
    }
  }
}

// ---------------- persistent recurrence v5: coalesced gather + LDS restage ----------------
// 256 WGs: replica = bid&7 (16 batches), wgc = bid>>3 (32 cols). Wave = K-quarter.
// W_hh frags in registers. Sync = round-3 proven scheme: agent-scope h stores,
// per-WG counter (4 wave-posts/step) on own 64B line, readers poll 32 counters.
// NEW: h gather is COALESCED (16x global_load_dwordx4 sc0 sc1, 1KB/instr) into
// an own-wave LDS quarter (no barrier needed; DS in-order per wave), MFMA
// A-frags read from LDS with XOR swizzle (idx ^= (row&7)<<2) -> ~conflict-free.
// Parallel 4-wave epilogue (validated in round 4). One barrier/step.
template <typename XPT>
__global__ __launch_bounds__(256, 1) void rnn_persist(
    const ushort* __restrict__ Whi, const ushort* __restrict__ Wlo,
    const XPT* __restrict__ xp,
    u32* __restrict__ hpk,   // [2][B_][H_] packed bf16 hi|lo
    u32* __restrict__ cnt,   // [256][16] 64B-spaced per-WG counters
    float* __restrict__ out) {
  __shared__ __align__(16) u32 stage[4 * 16 * 256];      // 64 KB
  __shared__ __align__(16) f32x4 red[2][4][2][64];       // 16 KB

  const int bid = blockIdx.x;
  const int rep = bid & 7;    // batches [rep*16, rep*16+16)
  const int wgc = bid >> 3;   // cols [wgc*32, wgc*32+32)
  const int tid = threadIdx.x;
  const int lane = tid & 63;
  const int kq = tid >> 6;    // wave = K-quarter
  const int r16 = lane & 15;
  const int kg = lane >> 4;   // 0..3
  const int nf_e = kq & 1;    // epilogue: nf slice
  const int rh_e = kq >> 1;   // epilogue: row pair

  // ---- preload W fragments into registers (128 VGPR) ----
  bf16x8 wbh[8][2], wbl[8][2];
#pragma unroll
  for (int ks = 0; ks < 8; ++ks) {
#pragma unroll
    for (int nf = 0; nf < 2; ++nf) {
      int col = wgc * 32 + nf * 16 + r16;
      int k = kq * 256 + ks * 32 + kg * 8;
      wbh[ks][nf] = *(const bf16x8*)(Whi + (size_t)col * H_ + k);
      wbl[ks][nf] = *(const bf16x8*)(Wlo + (size_t)col * H_ + k);
    }
  }

  const int erow0 = rep * 16 + kg * 4 + rh_e * 2;
  const int ecol = wgc * 32 + nf_e * 16 + r16;
  u32* mycnt = cnt + (size_t)(rep * 32 + wgc) * 16;
  const u32* pollbase = cnt + (size_t)(rep * 32) * 16;
  // stage region for this wave; frag-read swizzle = (row&7)<<2 (16B units)
  const int sbase = kq * (16 * 256);

  for (int t = 0; t < T_; ++t) {
    const u32* Hq = hpk + (size_t)(t & 1) * (B_ * H_);
    u32* Hn = hpk + (size_t)((t + 1) & 1) * (B_ * H_);

    // ---- poll: all 32 WGs of replica posted 4 wave-completions for t-1 ----
    const u32 target = 4u * (u32)t;
    if (t) {
      for (;;) {
        u32 v = 0xFFFFFFFFu;
        if (lane < 32)
          v = __hip_atomic_load(pollbase + (size_t)lane * 16,
                                __ATOMIC_RELAXED, __HIP_MEMORY_SCOPE_AGENT);
        if (__all((int)(v >= target))) break;
        __builtin_amdgcn_s_sleep(1);
      }
    }

    // xp prefetch (normal cached loads; latency overlaps the gather)
    float xpv[2];
#pragma unroll
    for (int e = 0; e < 2; ++e)
      xpv[e] = load_xp(xp + (size_t)t * (B_ * H_) + (size_t)(erow0 + e) * H_ + ecol);

    // ---- coalesced gather: wave kq pulls its 16-row x 256-col u32 quarter ----
    u32x4 g[16];
    {
      const u32* gb = Hq + (size_t)rep * 16 * H_ + kq * 256 + lane * 4;
#pragma unroll
      for (int i = 0; i < 16; ++i) {
        const u32* a = gb + (size_t)i * H_;
        asm volatile("global_load_dwordx4 %0, %1, off sc0 sc1"
                     : "=&v"(g[i]) : "v"(a) : "memory");
      }
    }
    asm volatile("s_waitcnt vmcnt(0)" ::: "memory");
    __builtin_amdgcn_sched_barrier(0);

    // ---- stage into own-wave LDS region (swizzled; row uniform per instr) ----
#pragma unroll
    for (int i = 0; i < 16; ++i) {
      int idx = sbase + i * 256 + ((lane * 4) ^ ((i & 7) << 2));
      *(u32x4*)&stage[idx] = g[i];
    }

    // ---- A-frags from LDS + MFMA (DS ops in-order per wave; no barrier) ----
    f32x4 acc[2] = {};
    const int rbase = sbase + r16 * 256;
    const int s = (r16 & 7) << 2;
#pragma unroll
    for (int ks = 0; ks < 8; ++ks) {
      int colq = ks * 32 + kg * 8;
      u32x4 d0 = *(const u32x4*)&stage[rbase + ((colq) ^ s)];
      u32x4 d1 = *(const u32x4*)&stage[rbase + ((colq + 4) ^ s)];
      union { u32 u[4]; bf16x8 v; } ah, al;
      ah.u[0] = __builtin_amdgcn_perm(d0[1], d0[0], 0x05040100u);
      ah.u[1] = __builtin_amdgcn_perm(d0[3], d0[2], 0x05040100u);
      ah.u[2] = __builtin_amdgcn_perm(d1[1], d1[0], 0x05040100u);
      ah.u[3] = __builtin_amdgcn_perm(d1[3], d1[2], 0x05040100u);
      al.u[0] = __builtin_amdgcn_perm(d0[1], d0[0], 0x07060302u);
      al.u[1] = __builtin_amdgcn_perm(d0[3], d0[2], 0x07060302u);
      al.u[2] = __builtin_amdgcn_perm(d1[1], d1[0], 0x07060302u);
      al.u[3] = __builtin_amdgcn_perm(d1[3], d1[2], 0x07060302u);
#pragma unroll
      for (int nf = 0; nf < 2; ++nf) {
        acc[nf] = __builtin_amdgcn_mfma_f32_16x16x32_bf16(ah.v, wbh[ks][nf], acc[nf], 0, 0, 0);
        acc[nf] = __builtin_amdgcn_mfma_f32_16x16x32_bf16(al.v, wbh[ks][nf], acc[nf], 0, 0, 0);
        acc[nf] = __builtin_amdgcn_mfma_f32_16x16x32_bf16(ah.v, wbl[ks][nf], acc[nf], 0, 0, 0);
      }
    }

    // ---- all-to-all K reduce (parity double-buffered, one barrier) ----
    const int par = t & 1;
    red[par][kq][0][lane] = acc[0];
    red[par][kq][1][lane] = acc[1];
    __syncthreads();

    // ---- parallel epilogue: each wave 2 outputs/lane (validated round 4) ----
#pragma unroll
    for (int e = 0; e < 2; ++e) {
      int r = rh_e * 2 + e;
      float sum = red[par][0][nf_e][lane][r] + red[par][1][nf_e][lane][r]
                + red[par][2][nf_e][lane][r] + red[par][3][nf_e][lane][r];
      float pre = sum + xpv[e];
      float hn = tanhf(pre);
      ushort hb = f2bf(hn);
      ushort lb = f2bf(hn - bf2f(hb));
      u32 pk = (u32)hb | ((u32)lb << 16);
      __hip_atomic_store(Hn + (size_t)(erow0 + e) * H_ + ecol, pk,
                         __ATOMIC_RELAXED, __HIP_MEMORY_SCOPE_AGENT);
      if (t == T_ - 1) out[(size_t)(erow0 + e) * H_ + ecol] = hn;
    }

    // ---- completion: drain stores, each wave bumps the WG counter ----
    asm volatile("s_waitcnt vmcnt(0)" ::: "memory");
    __builtin_amdgcn_sched_barrier(0);
    if (lane == 0) atomicAdd(mycnt, 1u);  // device-scope (LLC) — matches poll
  }
}

// ---------------- launch ----------------
extern "C" void kernel_launch(void* const* d_in, const int* in_sizes, int n_in,
                              void* d_out, int out_size, void* d_ws, size_t ws_size,
                              hipStream_t stream) {
  const float* x    = (const float*)d_in[0];
  const float* W_ih = (const float*)d_in[1];
  const float* W_hh = (const float*)d_in[2];
  const float* b_ih = (const float*)d_in[3];
  const float* b_hh = (const float*)d_in[4];
  float* out = (float*)d_out;

  const size_t xp_f32_bytes = (size_t)T_ * B_ * H_ * 4;   // 256 MB
  const size_t xp_bf_bytes  = xp_f32_bytes / 2;           // 128 MB
  const size_t wsp_bytes    = 2 * (size_t)H_ * H_ * 2;    // 4 MB (hi+lo)
  const size_t hpk_bytes    = 2 * (size_t)B_ * H_ * 4;    // 1 MB packed dbuf
  const size_t cnt_bytes    = 256 * 64;                   // 16 KB

  bool fp32xp = ws_size >= xp_f32_bytes + wsp_bytes + hpk_bytes + cnt_bytes;
  bool bf16xp = !fp32xp && ws_size >= xp_bf_bytes + wsp_bytes + hpk_bytes + cnt_bytes;
  if (!fp32xp && !bf16xp) return;

  char* p = (char*)d_ws;
  size_t xp_bytes = fp32xp ? xp_f32_bytes : xp_bf_bytes;
  char* xp_raw = p;                       p += xp_bytes;
  ushort* Whi = (ushort*)p;               p += (size_t)H_ * H_ * 2;
  ushort* Wlo = (ushort*)p;               p += (size_t)H_ * H_ * 2;
  u32* hpk = (u32*)p;                     p += hpk_bytes;
  u32* cnt = (u32*)p;

  // 1) split W_hh
  {
    int n = H_ * H_;
    wsplit_kernel<<<(n + 255) / 256, 256, 0, stream>>>(W_hh, Whi, Wlo, n);
  }
  // 2) zero hpk + counters (contiguous; re-done every launch)
  {
    int n4 = (int)((hpk_bytes + cnt_bytes) / 16);
    hzero_kernel<<<(n4 + 255) / 256, 256, 0, stream>>>((uint4*)hpk, n4);
  }
  // 3) xp GEMM
  dim3 gxp(512, 8);
  if (fp32xp)
    xp_gemm<float><<<gxp, 256, 0, stream>>>(x, W_ih, b_ih, b_hh, (float*)xp_raw);
  else
    xp_gemm<ushort><<<gxp, 256, 0, stream>>>(x, W_ih, b_ih, b_hh, (ushort*)xp_raw);

  // 4) persistent recurrence (256 WGs, 1 WG/CU)
  if (fp32xp)
    rnn_persist<float><<<256, 256, 0, stream>>>(Whi, Wlo, (const float*)xp_raw,
                                                hpk, cnt, out);
  else
    rnn_persist<ushort><<<256, 256, 0, stream>>>(Whi, Wlo, (const ushort*)xp_raw,
                                                 hpk, cnt, out);
}

// Round 8
// 2292.230 us; speedup vs baseline: 3.5165x; 1.2066x over previous
//
#include <hip/hip_runtime.h>
#include <stdint.h>

#define B_ 128
#define T_ 512
#define D_ 1024
#define H_ 1024

typedef __attribute__((ext_vector_type(8))) short bf16x8;
typedef __attribute__((ext_vector_type(4))) float f32x4;
typedef unsigned int u32;
typedef unsigned long long u64;
typedef __attribute__((ext_vector_type(4))) u32 u32x4;

__device__ __forceinline__ ushort f2bf(float f) {
  union { float f; uint32_t u; } v; v.f = f;
  uint32_t u = v.u + 0x7FFFu + ((v.u >> 16) & 1u);
  return (ushort)(u >> 16);
}
__device__ __forceinline__ float bf2f(ushort s) {
  union { uint32_t u; float f; } v; v.u = ((uint32_t)s) << 16;
  return v.f;
}

__device__ __forceinline__ void store_xp(float* p, float v) { *p = v; }
__device__ __forceinline__ void store_xp(ushort* p, float v) { *p = f2bf(v); }
__device__ __forceinline__ float load_xp(const float* p) { return *p; }
__device__ __forceinline__ float load_xp(const ushort* p) { return bf2f(*p); }

// ---------------- W_hh -> (hi, lo) bf16 split ----------------
__global__ void wsplit_kernel(const float* __restrict__ W,
                              ushort* __restrict__ hi, ushort* __restrict__ lo,
                              int n) {
  int i = blockIdx.x * blockDim.x + threadIdx.x;
  if (i < n) {
    float w = W[i];
    ushort h = f2bf(w);
    hi[i] = h;
    lo[i] = f2bf(w - bf2f(h));
  }
}

// ---------------- zero workspace region ----------------
__global__ void hzero_kernel(uint4* __restrict__ p, int n4) {
  int i = blockIdx.x * blockDim.x + threadIdx.x;
  if (i < n4) p[i] = make_uint4(0, 0, 0, 0);
}

// ---------------- xp = x @ W_ih^T + b_ih + b_hh, stored [T,B,H] ----------------
template <typename XPT>
__global__ __launch_bounds__(256) void xp_gemm(
    const float* __restrict__ x, const float* __restrict__ Wih,
    const float* __restrict__ bih, const float* __restrict__ bhh,
    XPT* __restrict__ xp) {
  __shared__ __align__(16) ushort As[128][40];
  __shared__ __align__(16) ushort Bs[128][40];
  const int tid = threadIdx.x;
  const int lane = tid & 63;
  const int w = tid >> 6;
  const int wm = w >> 1, wn = w & 1;
  const int bm = blockIdx.x;  // 512 M-tiles
  const int bn = blockIdx.y;  // 8 N-tiles

  f32x4 acc[4][4] = {};

  for (int kt = 0; kt < D_ / 32; ++kt) {
    __syncthreads();
#pragma unroll
    for (int i = 0; i < 4; ++i) {
      int c = tid + i * 256;      // 0..1023
      int isB = c >> 9;           // 0: A chunk, 1: B chunk
      int cc = c & 511;
      int row = cc >> 2;          // 0..127
      int col8 = (cc & 3) << 3;   // 0,8,16,24
      const float* src = isB
          ? (Wih + (size_t)(bn * 128 + row) * D_ + kt * 32 + col8)
          : (x + (size_t)(bm * 128 + row) * D_ + kt * 32 + col8);
      float4 f0 = *(const float4*)(src);
      float4 f1 = *(const float4*)(src + 4);
      uint32_t p0 = (uint32_t)f2bf(f0.x) | ((uint32_t)f2bf(f0.y) << 16);
      uint32_t p1 = (uint32_t)f2bf(f0.z) | ((uint32_t)f2bf(f0.w) << 16);
      uint32_t p2 = (uint32_t)f2bf(f1.x) | ((uint32_t)f2bf(f1.y) << 16);
      uint32_t p3 = (uint32_t)f2bf(f1.z) | ((uint32_t)f2bf(f1.w) << 16);
      uint4 pk = make_uint4(p0, p1, p2, p3);
      ushort* dst = isB ? &Bs[row][col8] : &As[row][col8];
      *(uint4*)dst = pk;
    }
    __syncthreads();

    bf16x8 af[4], bfr[4];
#pragma unroll
    for (int fm = 0; fm < 4; ++fm)
      af[fm] = *(const bf16x8*)&As[wm * 64 + fm * 16 + (lane & 15)][(lane >> 4) * 8];
#pragma unroll
    for (int fn = 0; fn < 4; ++fn)
      bfr[fn] = *(const bf16x8*)&Bs[wn * 64 + fn * 16 + (lane & 15)][(lane >> 4) * 8];
#pragma unroll
    for (int fm = 0; fm < 4; ++fm)
#pragma unroll
      for (int fn = 0; fn < 4; ++fn)
        acc[fm][fn] = __builtin_amdgcn_mfma_f32_16x16x32_bf16(
            af[fm], bfr[fn], acc[fm][fn], 0, 0, 0);
  }

  float bias[4];
#pragma unroll
  for (int fn = 0; fn < 4; ++fn) {
    int j = bn * 128 + wn * 64 + fn * 16 + (lane & 15);
    bias[fn] = bih[j] + bhh[j];
  }
#pragma unroll
  for (int fm = 0; fm < 4; ++fm) {
#pragma unroll
    for (int r = 0; r < 4; ++r) {
      int m = bm * 128 + wm * 64 + fm * 16 + ((lane >> 4) * 4) + r;
      int t = m & (T_ - 1);
      int b = m >> 9;  // m / T_
      size_t base = (size_t)t * (B_ * H_) + (size_t)b * H_;
#pragma unroll
      for (int fn = 0; fn < 4; ++fn) {
        int j = bn * 128 + wn * 64 + fn * 16 + (lane & 15);
        store_xp(xp + base + j, acc[fm][fn][r] + bias[fn]);
      }
    }
  }
}

// ---------------- persistent recurrence v6: per-wave producer poll ----------------
// 256 WGs: replica = bid&7 (16 batches), wgc = bid>>3 (32 cols). Wave = K-quarter.
// Wave kq's quarter (cols kq*256..+256) is produced by WGs wgc'=kq*8..+7 ->
// each wave polls ONLY those 8 counters, then gathers+MFMAs immediately
// (overlaps straggler wait). SAFETY: pre-epilogue __syncthreads joins the 4
// waves whose poll sets union to all 32 WGs, so h-buffer writes still happen
// only after the whole domain finished step t-1 (round-7 invariant intact).
// Epilogue red reads are vector f32x4 (conflict-free) + uniform-select.
template <typename XPT>
__global__ __launch_bounds__(256, 1) void rnn_persist(
    const ushort* __restrict__ Whi, const ushort* __restrict__ Wlo,
    const XPT* __restrict__ xp,
    u32* __restrict__ hpk,   // [2][B_][H_] packed bf16 hi|lo
    u32* __restrict__ cnt,   // [256][16] 64B-spaced per-WG counters
    float* __restrict__ out) {
  __shared__ __align__(16) u32 stage[4 * 16 * 256];      // 64 KB
  __shared__ __align__(16) f32x4 red[2][4][2][64];       // 16 KB

  const int bid = blockIdx.x;
  const int rep = bid & 7;    // batches [rep*16, rep*16+16)
  const int wgc = bid >> 3;   // cols [wgc*32, wgc*32+32)
  const int tid = threadIdx.x;
  const int lane = tid & 63;
  const int kq = tid >> 6;    // wave = K-quarter
  const int r16 = lane & 15;
  const int kg = lane >> 4;   // 0..3
  const int nf_e = kq & 1;    // epilogue: nf slice
  const int rh_e = kq >> 1;   // epilogue: row pair

  // ---- preload W fragments into registers (128 VGPR) ----
  bf16x8 wbh[8][2], wbl[8][2];
#pragma unroll
  for (int ks = 0; ks < 8; ++ks) {
#pragma unroll
    for (int nf = 0; nf < 2; ++nf) {
      int col = wgc * 32 + nf * 16 + r16;
      int k = kq * 256 + ks * 32 + kg * 8;
      wbh[ks][nf] = *(const bf16x8*)(Whi + (size_t)col * H_ + k);
      wbl[ks][nf] = *(const bf16x8*)(Wlo + (size_t)col * H_ + k);
    }
  }

  const int erow0 = rep * 16 + kg * 4 + rh_e * 2;
  const int ecol = wgc * 32 + nf_e * 16 + r16;
  u32* mycnt = cnt + (size_t)(rep * 32 + wgc) * 16;
  // wave kq's 8 producers: WGs (rep, kq*8 + 0..7); 8 lanes per counter line
  const u32* mypoll = cnt + (size_t)(rep * 32 + kq * 8 + (lane & 7)) * 16;
  const int sbase = kq * (16 * 256);

  for (int t = 0; t < T_; ++t) {
    const u32* Hq = hpk + (size_t)(t & 1) * (B_ * H_);
    u32* Hn = hpk + (size_t)((t + 1) & 1) * (B_ * H_);

    // ---- per-wave poll: this quarter's 8 producers done with step t-1 ----
    const u32 target = 4u * (u32)t;
    if (t) {
      for (;;) {
        u32 v = __hip_atomic_load(mypoll, __ATOMIC_RELAXED, __HIP_MEMORY_SCOPE_AGENT);
        if (__all((int)(v >= target))) break;
        __builtin_amdgcn_s_sleep(1);
      }
    }

    // xp prefetch (issued first -> oldest in vmcnt order)
    float xpv[2];
#pragma unroll
    for (int e = 0; e < 2; ++e)
      xpv[e] = load_xp(xp + (size_t)t * (B_ * H_) + (size_t)(erow0 + e) * H_ + ecol);

    // ---- coalesced gather: wave kq pulls its 16-row x 256-col u32 quarter ----
    u32x4 g[16];
    {
      const u32* gb = Hq + (size_t)rep * 16 * H_ + kq * 256 + lane * 4;
#pragma unroll
      for (int i = 0; i < 16; ++i) {
        const u32* a = gb + (size_t)i * H_;
        asm volatile("global_load_dwordx4 %0, %1, off sc0 sc1"
                     : "=&v"(g[i]) : "v"(a) : "memory");
      }
    }
    // chunked drain: xp(2) + 16 gathers outstanding; vmcnt(8) = oldest 10 done
    asm volatile("s_waitcnt vmcnt(8)" ::: "memory");
    __builtin_amdgcn_sched_barrier(0);
#pragma unroll
    for (int i = 0; i < 8; ++i) {
      int idx = sbase + i * 256 + ((lane * 4) ^ ((i & 7) << 2));
      *(u32x4*)&stage[idx] = g[i];
    }
    asm volatile("s_waitcnt vmcnt(0)" ::: "memory");
    __builtin_amdgcn_sched_barrier(0);
#pragma unroll
    for (int i = 8; i < 16; ++i) {
      int idx = sbase + i * 256 + ((lane * 4) ^ ((i & 7) << 2));
      *(u32x4*)&stage[idx] = g[i];
    }

    // ---- A-frags from LDS + MFMA (DS in-order per wave; no barrier) ----
    f32x4 acc[2] = {};
    const int rbase = sbase + r16 * 256;
    const int s = (r16 & 7) << 2;
#pragma unroll
    for (int ks = 0; ks < 8; ++ks) {
      int colq = ks * 32 + kg * 8;
      u32x4 d0 = *(const u32x4*)&stage[rbase + ((colq) ^ s)];
      u32x4 d1 = *(const u32x4*)&stage[rbase + ((colq + 4) ^ s)];
      union { u32 u[4]; bf16x8 v; } ah, al;
      ah.u[0] = __builtin_amdgcn_perm(d0[1], d0[0], 0x05040100u);
      ah.u[1] = __builtin_amdgcn_perm(d0[3], d0[2], 0x05040100u);
      ah.u[2] = __builtin_amdgcn_perm(d1[1], d1[0], 0x05040100u);
      ah.u[3] = __builtin_amdgcn_perm(d1[3], d1[2], 0x05040100u);
      al.u[0] = __builtin_amdgcn_perm(d0[1], d0[0], 0x07060302u);
      al.u[1] = __builtin_amdgcn_perm(d0[3], d0[2], 0x07060302u);
      al.u[2] = __builtin_amdgcn_perm(d1[1], d1[0], 0x07060302u);
      al.u[3] = __builtin_amdgcn_perm(d1[3], d1[2], 0x07060302u);
#pragma unroll
      for (int nf = 0; nf < 2; ++nf) {
        acc[nf] = __builtin_amdgcn_mfma_f32_16x16x32_bf16(ah.v, wbh[ks][nf], acc[nf], 0, 0, 0);
        acc[nf] = __builtin_amdgcn_mfma_f32_16x16x32_bf16(al.v, wbh[ks][nf], acc[nf], 0, 0, 0);
        acc[nf] = __builtin_amdgcn_mfma_f32_16x16x32_bf16(ah.v, wbl[ks][nf], acc[nf], 0, 0, 0);
      }
    }

    // ---- all-to-all K reduce (parity double-buffered, one barrier) ----
    const int par = t & 1;
    red[par][kq][0][lane] = acc[0];
    red[par][kq][1][lane] = acc[1];
    __syncthreads();   // joins all 4 waves => all 32 producers done (safety)

    // ---- parallel epilogue: vector red reads (conflict-free) ----
    {
      f32x4 sum = red[par][0][nf_e][lane];
      sum += red[par][1][nf_e][lane];
      sum += red[par][2][nf_e][lane];
      sum += red[par][3][nf_e][lane];
      // wave-uniform select of the 2 elements this wave owns (rh_e*2, +1)
      float s0 = rh_e ? sum[2] : sum[0];
      float s1 = rh_e ? sum[3] : sum[1];
      float pre0 = s0 + xpv[0];
      float pre1 = s1 + xpv[1];
      float h0 = tanhf(pre0);
      float h1 = tanhf(pre1);
      ushort hb0 = f2bf(h0), hb1 = f2bf(h1);
      u32 pk0 = (u32)hb0 | ((u32)f2bf(h0 - bf2f(hb0)) << 16);
      u32 pk1 = (u32)hb1 | ((u32)f2bf(h1 - bf2f(hb1)) << 16);
      __hip_atomic_store(Hn + (size_t)erow0 * H_ + ecol, pk0,
                         __ATOMIC_RELAXED, __HIP_MEMORY_SCOPE_AGENT);
      __hip_atomic_store(Hn + (size_t)(erow0 + 1) * H_ + ecol, pk1,
                         __ATOMIC_RELAXED, __HIP_MEMORY_SCOPE_AGENT);
      if (t == T_ - 1) {
        out[(size_t)erow0 * H_ + ecol] = h0;
        out[(size_t)(erow0 + 1) * H_ + ecol] = h1;
      }
    }

    // ---- completion: drain stores, each wave bumps the WG counter ----
    asm volatile("s_waitcnt vmcnt(0)" ::: "memory");
    __builtin_amdgcn_sched_barrier(0);
    if (lane == 0) atomicAdd(mycnt, 1u);  // device-scope (LLC) — matches poll
  }
}

// ---------------- launch ----------------
extern "C" void kernel_launch(void* const* d_in, const int* in_sizes, int n_in,
                              void* d_out, int out_size, void* d_ws, size_t ws_size,
                              hipStream_t stream) {
  const float* x    = (const float*)d_in[0];
  const float* W_ih = (const float*)d_in[1];
  const float* W_hh = (const float*)d_in[2];
  const float* b_ih = (const float*)d_in[3];
  const float* b_hh = (const float*)d_in[4];
  float* out = (float*)d_out;

  const size_t xp_f32_bytes = (size_t)T_ * B_ * H_ * 4;   // 256 MB
  const size_t xp_bf_bytes  = xp_f32_bytes / 2;           // 128 MB
  const size_t wsp_bytes    = 2 * (size_t)H_ * H_ * 2;    // 4 MB (hi+lo)
  const size_t hpk_bytes    = 2 * (size_t)B_ * H_ * 4;    // 1 MB packed dbuf
  const size_t cnt_bytes    = 256 * 64;                   // 16 KB

  bool fp32xp = ws_size >= xp_f32_bytes + wsp_bytes + hpk_bytes + cnt_bytes;
  bool bf16xp = !fp32xp && ws_size >= xp_bf_bytes + wsp_bytes + hpk_bytes + cnt_bytes;
  if (!fp32xp && !bf16xp) return;

  char* p = (char*)d_ws;
  size_t xp_bytes = fp32xp ? xp_f32_bytes : xp_bf_bytes;
  char* xp_raw = p;                       p += xp_bytes;
  ushort* Whi = (ushort*)p;               p += (size_t)H_ * H_ * 2;
  ushort* Wlo = (ushort*)p;               p += (size_t)H_ * H_ * 2;
  u32* hpk = (u32*)p;                     p += hpk_bytes;
  u32* cnt = (u32*)p;

  // 1) split W_hh
  {
    int n = H_ * H_;
    wsplit_kernel<<<(n + 255) / 256, 256, 0, stream>>>(W_hh, Whi, Wlo, n);
  }
  // 2) zero hpk + counters (contiguous; re-done every launch)
  {
    int n4 = (int)((hpk_bytes + cnt_bytes) / 16);
    hzero_kernel<<<(n4 + 255) / 256, 256, 0, stream>>>((uint4*)hpk, n4);
  }
  // 3) xp GEMM
  dim3 gxp(512, 8);
  if (fp32xp)
    xp_gemm<float><<<gxp, 256, 0, stream>>>(x, W_ih, b_ih, b_hh, (float*)xp_raw);
  else
    xp_gemm<ushort><<<gxp, 256, 0, stream>>>(x, W_ih, b_ih, b_hh, (ushort*)xp_raw);

  // 4) persistent recurrence (256 WGs, 1 WG/CU)
  if (fp32xp)
    rnn_persist<float><<<256, 256, 0, stream>>>(Whi, Wlo, (const float*)xp_raw,
                                                hpk, cnt, out);
  else
    rnn_persist<ushort><<<256, 256, 0, stream>>>(Whi, Wlo, (const ushort*)xp_raw,
                                                 hpk, cnt, out);
}